// Round 1
// baseline (2487.309 us; speedup 1.0000x reference)
//
#include <hip/hip_runtime.h>
#include <math.h>

#define DMODEL 1024
#define DSTATE 16
#define DCONV  4
#define DINNER 2048
#define BB     2
#define LL     2048
#define MROWS  (BB*LL)          // 4096
#define NXZ    (2*DINNER)       // 4096

// ---------------- generic fp32 tiled GEMM: C[M][N] = A[M][K] * B[K][N] ----------------
// 64x64 tile, BK=16, 256 threads, 4x4 micro-tile per thread.
__global__ __launch_bounds__(256) void gemm_f32_64(const float* __restrict__ A,
                                                   const float* __restrict__ B,
                                                   float* __restrict__ C,
                                                   int M, int N, int K) {
    __shared__ float As[16][64];
    __shared__ float Bs[16][64];
    const int tid = threadIdx.x;
    const int row0 = blockIdx.y * 64;
    const int col0 = blockIdx.x * 64;
    const int tr = tid >> 4;       // 0..15
    const int tc = tid & 15;       // 0..15
    float acc[4][4] = {{0.f,0.f,0.f,0.f},{0.f,0.f,0.f,0.f},{0.f,0.f,0.f,0.f},{0.f,0.f,0.f,0.f}};

    for (int k0 = 0; k0 < K; k0 += 16) {
        #pragma unroll
        for (int c = 0; c < 4; ++c) {
            int i  = tid + c * 256;
            int m  = i >> 4, kk = i & 15;          // As[kk][m] = A[row0+m][k0+kk]
            As[kk][m] = A[(size_t)(row0 + m) * K + k0 + kk];
            int kb = i >> 6, nb = i & 63;          // Bs[kb][nb] = B[k0+kb][col0+nb]
            Bs[kb][nb] = B[(size_t)(k0 + kb) * N + col0 + nb];
        }
        __syncthreads();
        #pragma unroll
        for (int kk = 0; kk < 16; ++kk) {
            float a[4], bfr[4];
            #pragma unroll
            for (int j = 0; j < 4; ++j) a[j]   = As[kk][tr * 4 + j];
            #pragma unroll
            for (int j = 0; j < 4; ++j) bfr[j] = Bs[kk][tc * 4 + j];
            #pragma unroll
            for (int i2 = 0; i2 < 4; ++i2)
                #pragma unroll
                for (int j = 0; j < 4; ++j)
                    acc[i2][j] += a[i2] * bfr[j];
        }
        __syncthreads();
    }
    #pragma unroll
    for (int i2 = 0; i2 < 4; ++i2)
        #pragma unroll
        for (int j = 0; j < 4; ++j)
            C[(size_t)(row0 + tr * 4 + i2) * N + col0 + tc * 4 + j] = acc[i2][j];
}

// ---------------- causal depthwise conv1d + SiLU ----------------
// xs[b][l][d] = silu( sum_{j=0..3} conv_w[d][j]*xc[b][l-3+j][d] + conv_b[d] )
// xc = xz[..., 0:2048]
__global__ __launch_bounds__(256) void conv_silu_kernel(const float* __restrict__ xz,
                                                        const float* __restrict__ conv_w,
                                                        const float* __restrict__ conv_b,
                                                        float* __restrict__ xs) {
    int idx = blockIdx.x * 256 + threadIdx.x;   // over B*L*DINNER
    int d = idx & (DINNER - 1);
    int l = (idx >> 11) & (LL - 1);
    int b = idx >> 22;
    float w0 = conv_w[d * 4 + 0], w1 = conv_w[d * 4 + 1];
    float w2 = conv_w[d * 4 + 2], w3 = conv_w[d * 4 + 3];
    const float* base = xz + (size_t)b * LL * NXZ + d;
    float s = conv_b[d];
    if (l - 3 >= 0) s += w0 * base[(size_t)(l - 3) * NXZ];
    if (l - 2 >= 0) s += w1 * base[(size_t)(l - 2) * NXZ];
    if (l - 1 >= 0) s += w2 * base[(size_t)(l - 1) * NXZ];
    s += w3 * base[(size_t)l * NXZ];
    float sig = 1.f / (1.f + __expf(-s));
    xs[idx] = s * sig;
}

// ---------------- dBC = xs @ W_x  (M=4096, K=2048, N=32) ----------------
// block = 256 threads = 8 rows x 32 cols
__global__ __launch_bounds__(256) void xproj_kernel(const float* __restrict__ xs,
                                                    const float* __restrict__ W_x,
                                                    float* __restrict__ dBC) {
    int row = blockIdx.x * 8 + (threadIdx.x >> 5);
    int n   = threadIdx.x & 31;
    const float* xr = xs + (size_t)row * DINNER;
    float acc = 0.f;
    for (int k = 0; k < DINNER; ++k)
        acc += xr[k] * W_x[k * 32 + n];
    dBC[(size_t)row * 32 + n] = acc;
}

// ---------------- delta = softplus(d_raw @ W_dt + b_dt)  (K=16) ----------------
__global__ __launch_bounds__(256) void dtproj_kernel(const float* __restrict__ dBC,
                                                     const float* __restrict__ W_dt,
                                                     const float* __restrict__ b_dt,
                                                     float* __restrict__ delta) {
    int idx = blockIdx.x * 256 + threadIdx.x;   // over B*L*DINNER
    int d = idx & (DINNER - 1);
    int row = idx >> 11;
    const float* dr = dBC + (size_t)row * 32;   // first 16 = d_raw
    float acc = b_dt[d];
    #pragma unroll
    for (int k = 0; k < DSTATE; ++k)
        acc += dr[k] * W_dt[k * DINNER + d];
    // softplus
    float sp = (acc > 20.f) ? acc : log1pf(expf(acc));
    delta[idx] = sp;
}

// ---------------- sequential scan + gate ----------------
// thread t: n = t&15, d = (t>>4)&2047, b = t>>15.  65536 threads.
// h_l = exp(delta*A[d][n]) * h_{l-1} + delta*B_l[n]*xs ; y = sum_n h*C_l[n] + D*xs ; yg = y*silu(z)
__global__ __launch_bounds__(256) void scan_kernel(const float* __restrict__ xz,
                                                   const float* __restrict__ xs,
                                                   const float* __restrict__ dBC,
                                                   const float* __restrict__ delta,
                                                   const float* __restrict__ A_log,
                                                   const float* __restrict__ Dp,
                                                   float* __restrict__ yg) {
    int t = blockIdx.x * 256 + threadIdx.x;
    int n = t & 15;
    int d = (t >> 4) & (DINNER - 1);
    int b = t >> 15;
    float An = -__expf(A_log[d * DSTATE + n]);
    float Dd = Dp[d];
    const float* dlt = delta + (size_t)b * LL * DINNER + d;
    const float* xsp = xs    + (size_t)b * LL * DINNER + d;
    const float* zp  = xz    + (size_t)b * LL * NXZ + DINNER + d;
    const float* bc  = dBC   + (size_t)b * LL * 32 + DSTATE + n;   // B (=C) entries
    float* yo = yg + (size_t)b * LL * DINNER + d;
    float h = 0.f;
    for (int l = 0; l < LL; ++l) {
        float dv = dlt[(size_t)l * DINNER];
        float xv = xsp[(size_t)l * DINNER];
        float Bn = bc[(size_t)l * 32];
        float dA = __expf(dv * An);
        h = dA * h + dv * Bn * xv;
        float p = h * Bn;                        // C = B
        p += __shfl_xor(p, 1);
        p += __shfl_xor(p, 2);
        p += __shfl_xor(p, 4);
        p += __shfl_xor(p, 8);
        if (n == 0) {
            float zv = zp[(size_t)l * NXZ];
            float sz = zv / (1.f + __expf(-zv));
            yo[(size_t)l * DINNER] = (p + Dd * xv) * sz;
        }
    }
}

extern "C" void kernel_launch(void* const* d_in, const int* in_sizes, int n_in,
                              void* d_out, int out_size, void* d_ws, size_t ws_size,
                              hipStream_t stream) {
    const float* x      = (const float*)d_in[0];
    const float* W_in   = (const float*)d_in[1];
    const float* conv_w = (const float*)d_in[2];
    const float* conv_b = (const float*)d_in[3];
    const float* W_x    = (const float*)d_in[4];
    const float* W_dt   = (const float*)d_in[5];
    const float* b_dt   = (const float*)d_in[6];
    const float* A_log  = (const float*)d_in[7];
    const float* Dp     = (const float*)d_in[8];
    const float* W_out  = (const float*)d_in[9];
    float* out = (float*)d_out;

    float* ws    = (float*)d_ws;
    float* xz    = ws;                       // 16,777,216
    float* xs    = xz + (size_t)MROWS * NXZ; //  8,388,608
    float* dBC   = xs + (size_t)MROWS * DINNER;       // 131,072
    float* delta = dBC + (size_t)MROWS * 32;          // 8,388,608
    float* yg    = delta + (size_t)MROWS * DINNER;    // 8,388,608

    // 1) xz = x @ W_in   (4096 x 1024) @ (1024 x 4096)
    gemm_f32_64<<<dim3(NXZ / 64, MROWS / 64), 256, 0, stream>>>(x, W_in, xz, MROWS, NXZ, DMODEL);
    // 2) xs = silu(causal depthwise conv(xc) + conv_b)
    conv_silu_kernel<<<(MROWS * DINNER) / 256, 256, 0, stream>>>(xz, conv_w, conv_b, xs);
    // 3) dBC = xs @ W_x
    xproj_kernel<<<MROWS / 8, 256, 0, stream>>>(xs, W_x, dBC);
    // 4) delta = softplus(d_raw @ W_dt + b_dt)
    dtproj_kernel<<<(MROWS * DINNER) / 256, 256, 0, stream>>>(dBC, W_dt, b_dt, delta);
    // 5) scan + einsum + D*xs + gate
    scan_kernel<<<(BB * DINNER * DSTATE) / 256, 256, 0, stream>>>(xz, xs, dBC, delta, A_log, Dp, yg);
    // 6) out = yg @ W_out   (4096 x 2048) @ (2048 x 1024)
    gemm_f32_64<<<dim3(DMODEL / 64, MROWS / 64), 256, 0, stream>>>(yg, W_out, out, MROWS, DMODEL, DINNER);
}

// Round 2
// 1064.126 us; speedup vs baseline: 2.3374x; 2.3374x over previous
//
#include <hip/hip_runtime.h>
#include <math.h>

#define DMODEL 1024
#define DSTATE 16
#define DCONV  4
#define DINNER 2048
#define BB     2
#define LL     2048
#define MROWS  (BB*LL)          // 4096
#define NXZ    (2*DINNER)       // 4096
#define NC     64               // chunks per sequence
#define CL     32               // chunk length (NC*CL == LL)

// ---------------- generic fp32 tiled GEMM: C[M][N] = A[M][K] * B[K][N] ----------------
__global__ __launch_bounds__(256) void gemm_f32_64(const float* __restrict__ A,
                                                   const float* __restrict__ B,
                                                   float* __restrict__ C,
                                                   int M, int N, int K) {
    __shared__ float As[16][64];
    __shared__ float Bs[16][64];
    const int tid = threadIdx.x;
    const int row0 = blockIdx.y * 64;
    const int col0 = blockIdx.x * 64;
    const int tr = tid >> 4;       // 0..15
    const int tc = tid & 15;       // 0..15
    float acc[4][4] = {{0.f,0.f,0.f,0.f},{0.f,0.f,0.f,0.f},{0.f,0.f,0.f,0.f},{0.f,0.f,0.f,0.f}};

    for (int k0 = 0; k0 < K; k0 += 16) {
        #pragma unroll
        for (int c = 0; c < 4; ++c) {
            int i  = tid + c * 256;
            int m  = i >> 4, kk = i & 15;
            As[kk][m] = A[(size_t)(row0 + m) * K + k0 + kk];
            int kb = i >> 6, nb = i & 63;
            Bs[kb][nb] = B[(size_t)(k0 + kb) * N + col0 + nb];
        }
        __syncthreads();
        #pragma unroll
        for (int kk = 0; kk < 16; ++kk) {
            float a[4], bfr[4];
            #pragma unroll
            for (int j = 0; j < 4; ++j) a[j]   = As[kk][tr * 4 + j];
            #pragma unroll
            for (int j = 0; j < 4; ++j) bfr[j] = Bs[kk][tc * 4 + j];
            #pragma unroll
            for (int i2 = 0; i2 < 4; ++i2)
                #pragma unroll
                for (int j = 0; j < 4; ++j)
                    acc[i2][j] += a[i2] * bfr[j];
        }
        __syncthreads();
    }
    #pragma unroll
    for (int i2 = 0; i2 < 4; ++i2)
        #pragma unroll
        for (int j = 0; j < 4; ++j)
            C[(size_t)(row0 + tr * 4 + i2) * N + col0 + tc * 4 + j] = acc[i2][j];
}

// ---------------- causal depthwise conv1d + SiLU ----------------
__global__ __launch_bounds__(256) void conv_silu_kernel(const float* __restrict__ xz,
                                                        const float* __restrict__ conv_w,
                                                        const float* __restrict__ conv_b,
                                                        float* __restrict__ xs) {
    int idx = blockIdx.x * 256 + threadIdx.x;   // over B*L*DINNER
    int d = idx & (DINNER - 1);
    int l = (idx >> 11) & (LL - 1);
    int b = idx >> 22;
    float w0 = conv_w[d * 4 + 0], w1 = conv_w[d * 4 + 1];
    float w2 = conv_w[d * 4 + 2], w3 = conv_w[d * 4 + 3];
    const float* base = xz + (size_t)b * LL * NXZ + d;
    float s = conv_b[d];
    if (l - 3 >= 0) s += w0 * base[(size_t)(l - 3) * NXZ];
    if (l - 2 >= 0) s += w1 * base[(size_t)(l - 2) * NXZ];
    if (l - 1 >= 0) s += w2 * base[(size_t)(l - 1) * NXZ];
    s += w3 * base[(size_t)l * NXZ];
    float sig = 1.f / (1.f + __expf(-s));
    xs[idx] = s * sig;
}

// ---------------- dBC = xs @ W_x  (M=4096, K=2048, N=32) ----------------
__global__ __launch_bounds__(256) void xproj_kernel(const float* __restrict__ xs,
                                                    const float* __restrict__ W_x,
                                                    float* __restrict__ dBC) {
    int row = blockIdx.x * 8 + (threadIdx.x >> 5);
    int n   = threadIdx.x & 31;
    const float* xr = xs + (size_t)row * DINNER;
    float acc = 0.f;
    for (int k = 0; k < DINNER; ++k)
        acc += xr[k] * W_x[k * 32 + n];
    dBC[(size_t)row * 32 + n] = acc;
}

// ---------------- chunked scan, phase A: per-chunk (prodA, h_partial) ----------------
// thread t: d = t&2047, c = (t>>11)&63, b = t>>17.  262144 threads.
// delta computed on the fly: softplus(dBC[row][0:16] @ W_dt[:,d] + b_dt[d])
__global__ __launch_bounds__(256) void scanA_kernel(const float* __restrict__ xs,
                                                    const float* __restrict__ dBC,
                                                    const float* __restrict__ A_log,
                                                    const float* __restrict__ W_dt,
                                                    const float* __restrict__ b_dt,
                                                    float* __restrict__ aProd,
                                                    float* __restrict__ hEnd) {
    int t = blockIdx.x * 256 + threadIdx.x;
    int d = t & (DINNER - 1);
    int c = (t >> 11) & (NC - 1);
    int b = t >> 17;
    float An[DSTATE], Wd[DSTATE], aP[DSTATE], h[DSTATE];
    #pragma unroll
    for (int n = 0; n < DSTATE; ++n) An[n] = -__expf(A_log[d * DSTATE + n]);
    #pragma unroll
    for (int k = 0; k < DSTATE; ++k) Wd[k] = W_dt[k * DINNER + d];
    float bd = b_dt[d];
    #pragma unroll
    for (int n = 0; n < DSTATE; ++n) { aP[n] = 1.f; h[n] = 0.f; }

    for (int i = 0; i < CL; ++i) {
        size_t row = (size_t)b * LL + c * CL + i;
        float rw[32];
        float4* rp = (float4*)rw;
        const float4* q = (const float4*)(dBC + row * 32);
        #pragma unroll
        for (int j = 0; j < 8; ++j) rp[j] = q[j];
        float dacc = bd;
        #pragma unroll
        for (int k = 0; k < DSTATE; ++k) dacc += rw[k] * Wd[k];
        float delta = (dacc > 20.f) ? dacc : log1pf(__expf(dacc));
        float xv = xs[row * DINNER + d];
        float dx = delta * xv;
        #pragma unroll
        for (int n = 0; n < DSTATE; ++n) {
            float a = __expf(delta * An[n]);
            aP[n] *= a;
            h[n] = a * h[n] + dx * rw[16 + n];
        }
    }
    size_t obase = ((size_t)((b * NC + c) * DSTATE)) * DINNER + d;
    #pragma unroll
    for (int n = 0; n < DSTATE; ++n) {
        aProd[obase + (size_t)n * DINNER] = aP[n];
        hEnd [obase + (size_t)n * DINNER] = h[n];
    }
}

// ---------------- phase B: serial scan over chunk aggregates; hEnd becomes carry-in ----------------
// thread t: d = t&2047, n = (t>>11)&15, b = t>>15.  65536 threads.
__global__ __launch_bounds__(256) void scanB_kernel(const float* __restrict__ aProd,
                                                    float* __restrict__ hEnd) {
    int t = blockIdx.x * 256 + threadIdx.x;
    int d = t & (DINNER - 1);
    int n = (t >> 11) & (DSTATE - 1);
    int b = t >> 15;
    float cur = 0.f;
    for (int c = 0; c < NC; ++c) {
        size_t idx = ((size_t)((b * NC + c) * DSTATE + n)) * DINNER + d;
        float a  = aProd[idx];
        float hh = hEnd[idx];
        hEnd[idx] = cur;          // carry-in for chunk c
        cur = a * cur + hh;
    }
}

// ---------------- phase C: recompute with carry, fuse C-dot + D*xs + z-gate ----------------
__global__ __launch_bounds__(256) void scanC_kernel(const float* __restrict__ xz,
                                                    const float* __restrict__ xs,
                                                    const float* __restrict__ dBC,
                                                    const float* __restrict__ A_log,
                                                    const float* __restrict__ W_dt,
                                                    const float* __restrict__ b_dt,
                                                    const float* __restrict__ Dp,
                                                    const float* __restrict__ hEnd,
                                                    float* __restrict__ yg) {
    int t = blockIdx.x * 256 + threadIdx.x;
    int d = t & (DINNER - 1);
    int c = (t >> 11) & (NC - 1);
    int b = t >> 17;
    float An[DSTATE], Wd[DSTATE], h[DSTATE];
    #pragma unroll
    for (int n = 0; n < DSTATE; ++n) An[n] = -__expf(A_log[d * DSTATE + n]);
    #pragma unroll
    for (int k = 0; k < DSTATE; ++k) Wd[k] = W_dt[k * DINNER + d];
    float bd = b_dt[d];
    float Dd = Dp[d];
    size_t obase = ((size_t)((b * NC + c) * DSTATE)) * DINNER + d;
    #pragma unroll
    for (int n = 0; n < DSTATE; ++n) h[n] = hEnd[obase + (size_t)n * DINNER];

    for (int i = 0; i < CL; ++i) {
        size_t row = (size_t)b * LL + c * CL + i;
        float rw[32];
        float4* rp = (float4*)rw;
        const float4* q = (const float4*)(dBC + row * 32);
        #pragma unroll
        for (int j = 0; j < 8; ++j) rp[j] = q[j];
        float dacc = bd;
        #pragma unroll
        for (int k = 0; k < DSTATE; ++k) dacc += rw[k] * Wd[k];
        float delta = (dacc > 20.f) ? dacc : log1pf(__expf(dacc));
        float xv = xs[row * DINNER + d];
        float dx = delta * xv;
        float p = 0.f;
        #pragma unroll
        for (int n = 0; n < DSTATE; ++n) {
            float a = __expf(delta * An[n]);
            h[n] = a * h[n] + dx * rw[16 + n];
            p += h[n] * rw[16 + n];
        }
        float y = p + Dd * xv;
        float zv = xz[row * NXZ + DINNER + d];
        float sz = zv / (1.f + __expf(-zv));
        yg[row * DINNER + d] = y * sz;
    }
}

extern "C" void kernel_launch(void* const* d_in, const int* in_sizes, int n_in,
                              void* d_out, int out_size, void* d_ws, size_t ws_size,
                              hipStream_t stream) {
    const float* x      = (const float*)d_in[0];
    const float* W_in   = (const float*)d_in[1];
    const float* conv_w = (const float*)d_in[2];
    const float* conv_b = (const float*)d_in[3];
    const float* W_x    = (const float*)d_in[4];
    const float* W_dt   = (const float*)d_in[5];
    const float* b_dt   = (const float*)d_in[6];
    const float* A_log  = (const float*)d_in[7];
    const float* Dp     = (const float*)d_in[8];
    const float* W_out  = (const float*)d_in[9];
    float* out = (float*)d_out;

    float* ws    = (float*)d_ws;
    float* xz    = ws;                                 // 16,777,216 floats
    float* xs    = xz + (size_t)MROWS * NXZ;           //  8,388,608
    float* dBC   = xs + (size_t)MROWS * DINNER;        //    131,072
    float* yg    = dBC + (size_t)MROWS * 32;           //  8,388,608
    float* aProd = yg + (size_t)MROWS * DINNER;        //  4,194,304
    float* hEnd  = aProd + (size_t)BB * NC * DSTATE * DINNER; // 4,194,304
    // total 42,074,112 floats = 168.3 MB (same as round 1)

    // 1) xz = x @ W_in
    gemm_f32_64<<<dim3(NXZ / 64, MROWS / 64), 256, 0, stream>>>(x, W_in, xz, MROWS, NXZ, DMODEL);
    // 2) xs = silu(causal depthwise conv(xc) + conv_b)
    conv_silu_kernel<<<(MROWS * DINNER) / 256, 256, 0, stream>>>(xz, conv_w, conv_b, xs);
    // 3) dBC = xs @ W_x
    xproj_kernel<<<MROWS / 8, 256, 0, stream>>>(xs, W_x, dBC);
    // 4) chunked scan (delta fused on the fly)
    scanA_kernel<<<(BB * NC * DINNER) / 256, 256, 0, stream>>>(xs, dBC, A_log, W_dt, b_dt, aProd, hEnd);
    scanB_kernel<<<(BB * DSTATE * DINNER) / 256, 256, 0, stream>>>(aProd, hEnd);
    scanC_kernel<<<(BB * NC * DINNER) / 256, 256, 0, stream>>>(xz, xs, dBC, A_log, W_dt, b_dt, Dp, hEnd, yg);
    // 5) out = yg @ W_out
    gemm_f32_64<<<dim3(DMODEL / 64, MROWS / 64), 256, 0, stream>>>(yg, W_out, out, MROWS, DMODEL, DINNER);
}

// Round 3
// 356.987 us; speedup vs baseline: 6.9675x; 2.9809x over previous
//
#include <hip/hip_runtime.h>
#include <hip/hip_bf16.h>
#include <math.h>

#define DMODEL 1024
#define DSTATE 16
#define DCONV  4
#define DINNER 2048
#define BB     2
#define LL     2048
#define MROWS  (BB*LL)          // 4096
#define NXZ    (2*DINNER)       // 4096
#define NC     64               // chunks per sequence
#define CL     32               // chunk length (NC*CL == LL)

typedef __attribute__((ext_vector_type(8))) short bf16x8;
typedef __attribute__((ext_vector_type(4))) float f32x4;

#define GLD_LDS16(g, l) __builtin_amdgcn_global_load_lds( \
    (const __attribute__((address_space(1))) void*)(g),   \
    (__attribute__((address_space(3))) void*)(l), 16, 0, 0)

// ---------------- f32 -> bf16 cast (4 elems/thread) ----------------
__global__ __launch_bounds__(256) void cast_bf16_kernel(const float* __restrict__ in,
                                                        __hip_bfloat16* __restrict__ out,
                                                        int n4) {
    int i = blockIdx.x * 256 + threadIdx.x;   // over n/4
    float4 v = *(const float4*)(in + (size_t)i * 4);
    union { __hip_bfloat16 h[4]; ushort4 u; } p;
    p.h[0] = __float2bfloat16(v.x);
    p.h[1] = __float2bfloat16(v.y);
    p.h[2] = __float2bfloat16(v.z);
    p.h[3] = __float2bfloat16(v.w);
    *(ushort4*)(out + (size_t)i * 4) = p.u;
}

// ---------------- W[K][N] f32 -> Wt[N][K] bf16 (32x32 LDS tile) ----------------
__global__ __launch_bounds__(256) void transpose_bf16_kernel(const float* __restrict__ W,
                                                             __hip_bfloat16* __restrict__ Wt,
                                                             int K, int N) {
    __shared__ __hip_bfloat16 tile[32][33];
    int n0 = blockIdx.x * 32, k0 = blockIdx.y * 32;
    int tx = threadIdx.x & 31, ty = threadIdx.x >> 5;   // ty 0..7
    #pragma unroll
    for (int j = 0; j < 4; ++j)
        tile[ty + j * 8][tx] = __float2bfloat16(W[(size_t)(k0 + ty + j * 8) * N + n0 + tx]);
    __syncthreads();
    #pragma unroll
    for (int j = 0; j < 4; ++j)
        Wt[(size_t)(n0 + ty + j * 8) * K + k0 + tx] = tile[tx][ty + j * 8];
}

// ---------------- bf16 MFMA GEMM: C[M][N] f32 = A[M][K] * Bt[N][K]^T ----------------
// 128x128 tile, BK=32, 256 threads (4 waves 2x2), 4x4 16x16x32 frags per wave.
__global__ __launch_bounds__(256) void gemm_bt_mfma(const __hip_bfloat16* __restrict__ A,
                                                    const __hip_bfloat16* __restrict__ Bt,
                                                    float* __restrict__ C,
                                                    int M, int N, int K) {
    __shared__ __hip_bfloat16 lA[128 * 32];
    __shared__ __hip_bfloat16 lB[128 * 32];
    const int tid  = threadIdx.x;
    const int lane = tid & 63;
    const int wid  = tid >> 6;
    const int row0 = blockIdx.y * 128;
    const int col0 = blockIdx.x * 128;
    const int wr = (wid >> 1) * 64;   // wave row origin in tile
    const int wc = (wid & 1) * 64;    // wave col origin in tile
    const int lr = lane & 15;
    const int kg = lane >> 4;

    f32x4 acc[4][4];
    #pragma unroll
    for (int m = 0; m < 4; ++m)
        #pragma unroll
        for (int n = 0; n < 4; ++n)
            acc[m][n] = (f32x4){0.f, 0.f, 0.f, 0.f};

    // per-thread staging geometry: chunk = wid*2+c covers LDS bytes [chunk*1024, +1024)
    // linear LDS [row][kk] (row-major 128x32) <=> element (chunk*64+lane)*8 maps to
    // row = (chunk*64+lane)>>2, q = (chunk*64+lane)&3, elems [q*8, q*8+8)
    for (int k0 = 0; k0 < K; k0 += 32) {
        #pragma unroll
        for (int c = 0; c < 2; ++c) {
            int chunk = wid * 2 + c;
            int idx = chunk * 64 + lane;
            int r = idx >> 2, q = idx & 3;
            GLD_LDS16(A  + (size_t)(row0 + r) * K + k0 + q * 8, lA + chunk * 512);
            GLD_LDS16(Bt + (size_t)(col0 + r) * K + k0 + q * 8, lB + chunk * 512);
        }
        __syncthreads();
        bf16x8 af[4], bv[4];
        #pragma unroll
        for (int m = 0; m < 4; ++m)
            af[m] = *reinterpret_cast<const bf16x8*>(lA + (wr + m * 16 + lr) * 32 + kg * 8);
        #pragma unroll
        for (int n = 0; n < 4; ++n)
            bv[n] = *reinterpret_cast<const bf16x8*>(lB + (wc + n * 16 + lr) * 32 + kg * 8);
        #pragma unroll
        for (int m = 0; m < 4; ++m)
            #pragma unroll
            for (int n = 0; n < 4; ++n)
                acc[m][n] = __builtin_amdgcn_mfma_f32_16x16x32_bf16(af[m], bv[n], acc[m][n], 0, 0, 0);
        __syncthreads();
    }
    // C/D layout: col = lane&15, row = (lane>>4)*4 + reg   [m89/m91 verified]
    #pragma unroll
    for (int m = 0; m < 4; ++m)
        #pragma unroll
        for (int n = 0; n < 4; ++n)
            #pragma unroll
            for (int r = 0; r < 4; ++r)
                C[(size_t)(row0 + wr + m * 16 + kg * 4 + r) * N + col0 + wc + n * 16 + lr] = acc[m][n][r];
}

// ---------------- causal depthwise conv1d + SiLU ----------------
__global__ __launch_bounds__(256) void conv_silu_kernel(const float* __restrict__ xz,
                                                        const float* __restrict__ conv_w,
                                                        const float* __restrict__ conv_b,
                                                        float* __restrict__ xs) {
    int idx = blockIdx.x * 256 + threadIdx.x;   // over B*L*DINNER
    int d = idx & (DINNER - 1);
    int l = (idx >> 11) & (LL - 1);
    int b = idx >> 22;
    float w0 = conv_w[d * 4 + 0], w1 = conv_w[d * 4 + 1];
    float w2 = conv_w[d * 4 + 2], w3 = conv_w[d * 4 + 3];
    const float* base = xz + (size_t)b * LL * NXZ + d;
    float s = conv_b[d];
    if (l - 3 >= 0) s += w0 * base[(size_t)(l - 3) * NXZ];
    if (l - 2 >= 0) s += w1 * base[(size_t)(l - 2) * NXZ];
    if (l - 1 >= 0) s += w2 * base[(size_t)(l - 1) * NXZ];
    s += w3 * base[(size_t)l * NXZ];
    float sig = 1.f / (1.f + __expf(-s));
    xs[idx] = s * sig;
}

// ---------------- dBC = xs @ W_x  (M=4096, K=2048, N=32) ----------------
__global__ __launch_bounds__(256) void xproj_kernel(const float* __restrict__ xs,
                                                    const float* __restrict__ W_x,
                                                    float* __restrict__ dBC) {
    int row = blockIdx.x * 8 + (threadIdx.x >> 5);
    int n   = threadIdx.x & 31;
    const float* xr = xs + (size_t)row * DINNER;
    float acc = 0.f;
    for (int k = 0; k < DINNER; ++k)
        acc += xr[k] * W_x[k * 32 + n];
    dBC[(size_t)row * 32 + n] = acc;
}

// ---------------- chunked scan, phase A ----------------
__global__ __launch_bounds__(256) void scanA_kernel(const float* __restrict__ xs,
                                                    const float* __restrict__ dBC,
                                                    const float* __restrict__ A_log,
                                                    const float* __restrict__ W_dt,
                                                    const float* __restrict__ b_dt,
                                                    float* __restrict__ aProd,
                                                    float* __restrict__ hEnd) {
    int t = blockIdx.x * 256 + threadIdx.x;
    int d = t & (DINNER - 1);
    int c = (t >> 11) & (NC - 1);
    int b = t >> 17;
    float An[DSTATE], Wd[DSTATE], aP[DSTATE], h[DSTATE];
    #pragma unroll
    for (int n = 0; n < DSTATE; ++n) An[n] = -__expf(A_log[d * DSTATE + n]);
    #pragma unroll
    for (int k = 0; k < DSTATE; ++k) Wd[k] = W_dt[k * DINNER + d];
    float bd = b_dt[d];
    #pragma unroll
    for (int n = 0; n < DSTATE; ++n) { aP[n] = 1.f; h[n] = 0.f; }

    for (int i = 0; i < CL; ++i) {
        size_t row = (size_t)b * LL + c * CL + i;
        float rw[32];
        float4* rp = (float4*)rw;
        const float4* q = (const float4*)(dBC + row * 32);
        #pragma unroll
        for (int j = 0; j < 8; ++j) rp[j] = q[j];
        float dacc = bd;
        #pragma unroll
        for (int k = 0; k < DSTATE; ++k) dacc += rw[k] * Wd[k];
        float delta = (dacc > 20.f) ? dacc : log1pf(__expf(dacc));
        float xv = xs[row * DINNER + d];
        float dx = delta * xv;
        #pragma unroll
        for (int n = 0; n < DSTATE; ++n) {
            float a = __expf(delta * An[n]);
            aP[n] *= a;
            h[n] = a * h[n] + dx * rw[16 + n];
        }
    }
    size_t obase = ((size_t)((b * NC + c) * DSTATE)) * DINNER + d;
    #pragma unroll
    for (int n = 0; n < DSTATE; ++n) {
        aProd[obase + (size_t)n * DINNER] = aP[n];
        hEnd [obase + (size_t)n * DINNER] = h[n];
    }
}

// ---------------- phase B: scan over chunk aggregates ----------------
__global__ __launch_bounds__(256) void scanB_kernel(const float* __restrict__ aProd,
                                                    float* __restrict__ hEnd) {
    int t = blockIdx.x * 256 + threadIdx.x;
    int d = t & (DINNER - 1);
    int n = (t >> 11) & (DSTATE - 1);
    int b = t >> 15;
    float cur = 0.f;
    for (int c = 0; c < NC; ++c) {
        size_t idx = ((size_t)((b * NC + c) * DSTATE + n)) * DINNER + d;
        float a  = aProd[idx];
        float hh = hEnd[idx];
        hEnd[idx] = cur;          // carry-in for chunk c
        cur = a * cur + hh;
    }
}

// ---------------- phase C: recompute with carry; fused C-dot + D*xs + z-gate; bf16 out ----------------
__global__ __launch_bounds__(256) void scanC_kernel(const float* __restrict__ xz,
                                                    const float* __restrict__ xs,
                                                    const float* __restrict__ dBC,
                                                    const float* __restrict__ A_log,
                                                    const float* __restrict__ W_dt,
                                                    const float* __restrict__ b_dt,
                                                    const float* __restrict__ Dp,
                                                    const float* __restrict__ hEnd,
                                                    __hip_bfloat16* __restrict__ ygb) {
    int t = blockIdx.x * 256 + threadIdx.x;
    int d = t & (DINNER - 1);
    int c = (t >> 11) & (NC - 1);
    int b = t >> 17;
    float An[DSTATE], Wd[DSTATE], h[DSTATE];
    #pragma unroll
    for (int n = 0; n < DSTATE; ++n) An[n] = -__expf(A_log[d * DSTATE + n]);
    #pragma unroll
    for (int k = 0; k < DSTATE; ++k) Wd[k] = W_dt[k * DINNER + d];
    float bd = b_dt[d];
    float Dd = Dp[d];
    size_t obase = ((size_t)((b * NC + c) * DSTATE)) * DINNER + d;
    #pragma unroll
    for (int n = 0; n < DSTATE; ++n) h[n] = hEnd[obase + (size_t)n * DINNER];

    for (int i = 0; i < CL; ++i) {
        size_t row = (size_t)b * LL + c * CL + i;
        float rw[32];
        float4* rp = (float4*)rw;
        const float4* q = (const float4*)(dBC + row * 32);
        #pragma unroll
        for (int j = 0; j < 8; ++j) rp[j] = q[j];
        float dacc = bd;
        #pragma unroll
        for (int k = 0; k < DSTATE; ++k) dacc += rw[k] * Wd[k];
        float delta = (dacc > 20.f) ? dacc : log1pf(__expf(dacc));
        float xv = xs[row * DINNER + d];
        float dx = delta * xv;
        float p = 0.f;
        #pragma unroll
        for (int n = 0; n < DSTATE; ++n) {
            float a = __expf(delta * An[n]);
            h[n] = a * h[n] + dx * rw[16 + n];
            p += h[n] * rw[16 + n];
        }
        float y = p + Dd * xv;
        float zv = xz[row * NXZ + DINNER + d];
        float sz = zv / (1.f + __expf(-zv));
        ygb[row * DINNER + d] = __float2bfloat16(y * sz);
    }
}

extern "C" void kernel_launch(void* const* d_in, const int* in_sizes, int n_in,
                              void* d_out, int out_size, void* d_ws, size_t ws_size,
                              hipStream_t stream) {
    const float* x      = (const float*)d_in[0];
    const float* W_in   = (const float*)d_in[1];
    const float* conv_w = (const float*)d_in[2];
    const float* conv_b = (const float*)d_in[3];
    const float* W_x    = (const float*)d_in[4];
    const float* W_dt   = (const float*)d_in[5];
    const float* b_dt   = (const float*)d_in[6];
    const float* A_log  = (const float*)d_in[7];
    const float* Dp     = (const float*)d_in[8];
    const float* W_out  = (const float*)d_in[9];
    float* out = (float*)d_out;

    float* ws    = (float*)d_ws;
    float* xz    = ws;                                  // 16,777,216 f
    float* xs    = xz + (size_t)MROWS * NXZ;            //  8,388,608 f
    float* dBC   = xs + (size_t)MROWS * DINNER;         //    131,072 f
    float* aProd = dBC + (size_t)MROWS * 32;            //  4,194,304 f
    float* hEnd  = aProd + (size_t)BB * NC * DSTATE * DINNER; // 4,194,304 f
    float* wott  = hEnd + (size_t)BB * NC * DSTATE * DINNER;  // W_out_t: 2,097,152 bf16 = 1,048,576 f
    float* alias = wott + (size_t)DMODEL * DINNER / 2;  // alias region: 4,194,304 f
    // phase 1: xb (4,194,304 bf16) | W_in_t (4,194,304 bf16)
    // phase 2: ygb (8,388,608 bf16)  -- xb/W_in_t dead by then
    __hip_bfloat16* xb     = (__hip_bfloat16*)alias;
    __hip_bfloat16* W_in_t = xb + (size_t)MROWS * DMODEL;
    __hip_bfloat16* ygb    = (__hip_bfloat16*)alias;
    __hip_bfloat16* W_out_t = (__hip_bfloat16*)wott;
    // total: 38,928,384 f = 155.7 MB

    // prep: casts + weight transposes
    cast_bf16_kernel<<<(MROWS * DMODEL) / (256 * 4), 256, 0, stream>>>(x, xb, MROWS * DMODEL / 4);
    transpose_bf16_kernel<<<dim3(NXZ / 32, DMODEL / 32), 256, 0, stream>>>(W_in, W_in_t, DMODEL, NXZ);
    transpose_bf16_kernel<<<dim3(DMODEL / 32, DINNER / 32), 256, 0, stream>>>(W_out, W_out_t, DINNER, DMODEL);

    // 1) xz = x @ W_in   (MFMA bf16, f32 out)
    gemm_bt_mfma<<<dim3(NXZ / 128, MROWS / 128), 256, 0, stream>>>(xb, W_in_t, xz, MROWS, NXZ, DMODEL);
    // 2) xs = silu(causal depthwise conv(xc) + conv_b)
    conv_silu_kernel<<<(MROWS * DINNER) / 256, 256, 0, stream>>>(xz, conv_w, conv_b, xs);
    // 3) dBC = xs @ W_x
    xproj_kernel<<<MROWS / 8, 256, 0, stream>>>(xs, W_x, dBC);
    // 4) chunked scan (delta fused on the fly); scanC writes bf16 ygb
    scanA_kernel<<<(BB * NC * DINNER) / 256, 256, 0, stream>>>(xs, dBC, A_log, W_dt, b_dt, aProd, hEnd);
    scanB_kernel<<<(BB * DSTATE * DINNER) / 256, 256, 0, stream>>>(aProd, hEnd);
    scanC_kernel<<<(BB * NC * DINNER) / 256, 256, 0, stream>>>(xz, xs, dBC, A_log, W_dt, b_dt, Dp, hEnd, ygb);
    // 5) out = yg @ W_out  (MFMA bf16, f32 out)
    gemm_bt_mfma<<<dim3(DMODEL / 128, MROWS / 128), 256, 0, stream>>>(ygb, W_out_t, out, MROWS, DMODEL, DINNER);
}

// Round 4
// 320.857 us; speedup vs baseline: 7.7521x; 1.1126x over previous
//
#include <hip/hip_runtime.h>
#include <hip/hip_bf16.h>
#include <math.h>

#define DMODEL 1024
#define DSTATE 16
#define DCONV  4
#define DINNER 2048
#define BB     2
#define LL     2048
#define MROWS  (BB*LL)          // 4096
#define NXZ    (2*DINNER)       // 4096
#define NC     64               // chunks per sequence
#define CL     32               // chunk length (NC*CL == LL)

typedef __attribute__((ext_vector_type(8))) short bf16x8;
typedef __attribute__((ext_vector_type(4))) float f32x4;

#define GLD_LDS16(g, l) __builtin_amdgcn_global_load_lds( \
    (const __attribute__((address_space(1))) void*)(g),   \
    (__attribute__((address_space(3))) void*)(l), 16, 0, 0)

__device__ __forceinline__ float softplus_fast(float x) {
    // softplus(x) = max(x,0) + log(1+exp(-|x|));  __logf/__expf = HW trans ops
    return fmaxf(x, 0.f) + __logf(1.f + __expf(-fabsf(x)));
}
__device__ __forceinline__ float sigmoid_fast(float x) {
    return __builtin_amdgcn_rcpf(1.f + __expf(-x));
}

// ---------------- f32 -> bf16 cast (4 elems/thread) ----------------
__global__ __launch_bounds__(256) void cast_bf16_kernel(const float* __restrict__ in,
                                                        __hip_bfloat16* __restrict__ out,
                                                        int n4) {
    int i = blockIdx.x * 256 + threadIdx.x;   // over n/4
    float4 v = *(const float4*)(in + (size_t)i * 4);
    union { __hip_bfloat16 h[4]; ushort4 u; } p;
    p.h[0] = __float2bfloat16(v.x);
    p.h[1] = __float2bfloat16(v.y);
    p.h[2] = __float2bfloat16(v.z);
    p.h[3] = __float2bfloat16(v.w);
    *(ushort4*)(out + (size_t)i * 4) = p.u;
}

// ---------------- W[K][N] f32 -> Wt[N][K] bf16 (32x32 LDS tile) ----------------
__global__ __launch_bounds__(256) void transpose_bf16_kernel(const float* __restrict__ W,
                                                             __hip_bfloat16* __restrict__ Wt,
                                                             int K, int N) {
    __shared__ __hip_bfloat16 tile[32][33];
    int n0 = blockIdx.x * 32, k0 = blockIdx.y * 32;
    int tx = threadIdx.x & 31, ty = threadIdx.x >> 5;   // ty 0..7
    #pragma unroll
    for (int j = 0; j < 4; ++j)
        tile[ty + j * 8][tx] = __float2bfloat16(W[(size_t)(k0 + ty + j * 8) * N + n0 + tx]);
    __syncthreads();
    #pragma unroll
    for (int j = 0; j < 4; ++j)
        Wt[(size_t)(n0 + ty + j * 8) * K + k0 + tx] = tile[tx][ty + j * 8];
}

// ---------------- bf16 MFMA GEMM: C[M][N] f32 = A[M][K] * Bt[N][K]^T ----------------
// 128x128 tile, BK=32, 256 threads (4 waves 2x2), 4x4 16x16x32 frags per wave.
__global__ __launch_bounds__(256) void gemm_bt_mfma(const __hip_bfloat16* __restrict__ A,
                                                    const __hip_bfloat16* __restrict__ Bt,
                                                    float* __restrict__ C,
                                                    int M, int N, int K) {
    __shared__ __hip_bfloat16 lA[128 * 32];
    __shared__ __hip_bfloat16 lB[128 * 32];
    const int tid  = threadIdx.x;
    const int lane = tid & 63;
    const int wid  = tid >> 6;
    const int row0 = blockIdx.y * 128;
    const int col0 = blockIdx.x * 128;
    const int wr = (wid >> 1) * 64;   // wave row origin in tile
    const int wc = (wid & 1) * 64;    // wave col origin in tile
    const int lr = lane & 15;
    const int kg = lane >> 4;

    f32x4 acc[4][4];
    #pragma unroll
    for (int m = 0; m < 4; ++m)
        #pragma unroll
        for (int n = 0; n < 4; ++n)
            acc[m][n] = (f32x4){0.f, 0.f, 0.f, 0.f};

    for (int k0 = 0; k0 < K; k0 += 32) {
        #pragma unroll
        for (int c = 0; c < 2; ++c) {
            int chunk = wid * 2 + c;
            int idx = chunk * 64 + lane;
            int r = idx >> 2, q = idx & 3;
            GLD_LDS16(A  + (size_t)(row0 + r) * K + k0 + q * 8, lA + chunk * 512);
            GLD_LDS16(Bt + (size_t)(col0 + r) * K + k0 + q * 8, lB + chunk * 512);
        }
        __syncthreads();
        bf16x8 af[4], bv[4];
        #pragma unroll
        for (int m = 0; m < 4; ++m)
            af[m] = *reinterpret_cast<const bf16x8*>(lA + (wr + m * 16 + lr) * 32 + kg * 8);
        #pragma unroll
        for (int n = 0; n < 4; ++n)
            bv[n] = *reinterpret_cast<const bf16x8*>(lB + (wc + n * 16 + lr) * 32 + kg * 8);
        #pragma unroll
        for (int m = 0; m < 4; ++m)
            #pragma unroll
            for (int n = 0; n < 4; ++n)
                acc[m][n] = __builtin_amdgcn_mfma_f32_16x16x32_bf16(af[m], bv[n], acc[m][n], 0, 0, 0);
        __syncthreads();
    }
    // C/D layout: col = lane&15, row = (lane>>4)*4 + reg   [m89/m91 verified]
    #pragma unroll
    for (int m = 0; m < 4; ++m)
        #pragma unroll
        for (int n = 0; n < 4; ++n)
            #pragma unroll
            for (int r = 0; r < 4; ++r)
                C[(size_t)(row0 + wr + m * 16 + kg * 4 + r) * N + col0 + wc + n * 16 + lr] = acc[m][n][r];
}

// ---------------- causal depthwise conv1d + SiLU ----------------
__global__ __launch_bounds__(256) void conv_silu_kernel(const float* __restrict__ xz,
                                                        const float* __restrict__ conv_w,
                                                        const float* __restrict__ conv_b,
                                                        float* __restrict__ xs) {
    int idx = blockIdx.x * 256 + threadIdx.x;   // over B*L*DINNER
    int d = idx & (DINNER - 1);
    int l = (idx >> 11) & (LL - 1);
    int b = idx >> 22;
    float w0 = conv_w[d * 4 + 0], w1 = conv_w[d * 4 + 1];
    float w2 = conv_w[d * 4 + 2], w3 = conv_w[d * 4 + 3];
    const float* base = xz + (size_t)b * LL * NXZ + d;
    float s = conv_b[d];
    if (l - 3 >= 0) s += w0 * base[(size_t)(l - 3) * NXZ];
    if (l - 2 >= 0) s += w1 * base[(size_t)(l - 2) * NXZ];
    if (l - 1 >= 0) s += w2 * base[(size_t)(l - 1) * NXZ];
    s += w3 * base[(size_t)l * NXZ];
    xs[idx] = s * sigmoid_fast(s);
}

// ---------------- dBC = xs @ W_x  (M=4096, K=2048, N=32) ----------------
__global__ __launch_bounds__(256) void xproj_kernel(const float* __restrict__ xs,
                                                    const float* __restrict__ W_x,
                                                    float* __restrict__ dBC) {
    int row = blockIdx.x * 8 + (threadIdx.x >> 5);
    int n   = threadIdx.x & 31;
    const float* xr = xs + (size_t)row * DINNER;
    float acc = 0.f;
    for (int k = 0; k < DINNER; ++k)
        acc += xr[k] * W_x[k * 32 + n];
    dBC[(size_t)row * 32 + n] = acc;
}

// ---------------- chunked scan, phase A ----------------
// thread t: d = t&2047, c = (t>>11)&63, b = t>>17.  262144 threads.
// aP[n] = exp(An * sum(delta)) [exp-of-sum]; h updated per step.
__global__ __launch_bounds__(256, 2) void scanA_kernel(const float* __restrict__ xs,
                                                       const float* __restrict__ dBC,
                                                       const float* __restrict__ A_log,
                                                       const float* __restrict__ W_dt,
                                                       const float* __restrict__ b_dt,
                                                       float* __restrict__ aProd,
                                                       float* __restrict__ hEnd) {
    int t = blockIdx.x * 256 + threadIdx.x;
    int d = t & (DINNER - 1);
    int c = (t >> 11) & (NC - 1);
    int b = t >> 17;
    float An[DSTATE], Wd[DSTATE], h[DSTATE];
    #pragma unroll
    for (int n = 0; n < DSTATE; ++n) An[n] = -__expf(A_log[d * DSTATE + n]);
    #pragma unroll
    for (int k = 0; k < DSTATE; ++k) Wd[k] = W_dt[k * DINNER + d];
    float bd = b_dt[d];
    float dsum = 0.f;
    #pragma unroll
    for (int n = 0; n < DSTATE; ++n) h[n] = 0.f;

    for (int i = 0; i < CL; ++i) {
        size_t row = (size_t)b * LL + c * CL + i;
        float rw[32];
        float4* rp = (float4*)rw;
        const float4* q = (const float4*)(dBC + row * 32);
        #pragma unroll
        for (int j = 0; j < 8; ++j) rp[j] = q[j];
        float dacc = bd;
        #pragma unroll
        for (int k = 0; k < DSTATE; ++k) dacc += rw[k] * Wd[k];
        float delta = softplus_fast(dacc);
        dsum += delta;
        float xv = xs[row * DINNER + d];
        float dx = delta * xv;
        #pragma unroll
        for (int n = 0; n < DSTATE; ++n) {
            float a = __expf(delta * An[n]);
            h[n] = a * h[n] + dx * rw[16 + n];
        }
    }
    size_t obase = ((size_t)((b * NC + c) * DSTATE)) * DINNER + d;
    #pragma unroll
    for (int n = 0; n < DSTATE; ++n) {
        aProd[obase + (size_t)n * DINNER] = __expf(dsum * An[n]);
        hEnd [obase + (size_t)n * DINNER] = h[n];
    }
}

// ---------------- phase B: scan over chunk aggregates ----------------
__global__ __launch_bounds__(256) void scanB_kernel(const float* __restrict__ aProd,
                                                    float* __restrict__ hEnd) {
    int t = blockIdx.x * 256 + threadIdx.x;
    int d = t & (DINNER - 1);
    int n = (t >> 11) & (DSTATE - 1);
    int b = t >> 15;
    float cur = 0.f;
    for (int c = 0; c < NC; ++c) {
        size_t idx = ((size_t)((b * NC + c) * DSTATE + n)) * DINNER + d;
        float a  = aProd[idx];
        float hh = hEnd[idx];
        hEnd[idx] = cur;          // carry-in for chunk c
        cur = a * cur + hh;
    }
}

// ---------------- phase C: recompute with carry; fused C-dot + D*xs + z-gate; bf16 out ----------------
__global__ __launch_bounds__(256, 2) void scanC_kernel(const float* __restrict__ xz,
                                                       const float* __restrict__ xs,
                                                       const float* __restrict__ dBC,
                                                       const float* __restrict__ A_log,
                                                       const float* __restrict__ W_dt,
                                                       const float* __restrict__ b_dt,
                                                       const float* __restrict__ Dp,
                                                       const float* __restrict__ hEnd,
                                                       __hip_bfloat16* __restrict__ ygb) {
    int t = blockIdx.x * 256 + threadIdx.x;
    int d = t & (DINNER - 1);
    int c = (t >> 11) & (NC - 1);
    int b = t >> 17;
    float An[DSTATE], Wd[DSTATE], h[DSTATE];
    #pragma unroll
    for (int n = 0; n < DSTATE; ++n) An[n] = -__expf(A_log[d * DSTATE + n]);
    #pragma unroll
    for (int k = 0; k < DSTATE; ++k) Wd[k] = W_dt[k * DINNER + d];
    float bd = b_dt[d];
    float Dd = Dp[d];
    size_t obase = ((size_t)((b * NC + c) * DSTATE)) * DINNER + d;
    #pragma unroll
    for (int n = 0; n < DSTATE; ++n) h[n] = hEnd[obase + (size_t)n * DINNER];

    for (int i = 0; i < CL; ++i) {
        size_t row = (size_t)b * LL + c * CL + i;
        float rw[32];
        float4* rp = (float4*)rw;
        const float4* q = (const float4*)(dBC + row * 32);
        #pragma unroll
        for (int j = 0; j < 8; ++j) rp[j] = q[j];
        float dacc = bd;
        #pragma unroll
        for (int k = 0; k < DSTATE; ++k) dacc += rw[k] * Wd[k];
        float delta = softplus_fast(dacc);
        float xv = xs[row * DINNER + d];
        float dx = delta * xv;
        float p = 0.f;
        #pragma unroll
        for (int n = 0; n < DSTATE; ++n) {
            float a = __expf(delta * An[n]);
            h[n] = a * h[n] + dx * rw[16 + n];
            p += h[n] * rw[16 + n];
        }
        float y = p + Dd * xv;
        float zv = xz[row * NXZ + DINNER + d];
        float sz = zv * sigmoid_fast(zv);
        ygb[row * DINNER + d] = __float2bfloat16(y * sz);
    }
}

extern "C" void kernel_launch(void* const* d_in, const int* in_sizes, int n_in,
                              void* d_out, int out_size, void* d_ws, size_t ws_size,
                              hipStream_t stream) {
    const float* x      = (const float*)d_in[0];
    const float* W_in   = (const float*)d_in[1];
    const float* conv_w = (const float*)d_in[2];
    const float* conv_b = (const float*)d_in[3];
    const float* W_x    = (const float*)d_in[4];
    const float* W_dt   = (const float*)d_in[5];
    const float* b_dt   = (const float*)d_in[6];
    const float* A_log  = (const float*)d_in[7];
    const float* Dp     = (const float*)d_in[8];
    const float* W_out  = (const float*)d_in[9];
    float* out = (float*)d_out;

    float* ws    = (float*)d_ws;
    float* xz    = ws;                                  // 16,777,216 f
    float* xs    = xz + (size_t)MROWS * NXZ;            //  8,388,608 f
    float* dBC   = xs + (size_t)MROWS * DINNER;         //    131,072 f
    float* aProd = dBC + (size_t)MROWS * 32;            //  4,194,304 f
    float* hEnd  = aProd + (size_t)BB * NC * DSTATE * DINNER; // 4,194,304 f
    float* wott  = hEnd + (size_t)BB * NC * DSTATE * DINNER;  // W_out_t: 2,097,152 bf16 = 1,048,576 f
    float* alias = wott + (size_t)DMODEL * DINNER / 2;  // alias region: 4,194,304 f
    __hip_bfloat16* xb     = (__hip_bfloat16*)alias;
    __hip_bfloat16* W_in_t = xb + (size_t)MROWS * DMODEL;
    __hip_bfloat16* ygb    = (__hip_bfloat16*)alias;
    __hip_bfloat16* W_out_t = (__hip_bfloat16*)wott;
    // total: 38,928,384 f = 155.7 MB

    // prep: casts + weight transposes
    cast_bf16_kernel<<<(MROWS * DMODEL) / (256 * 4), 256, 0, stream>>>(x, xb, MROWS * DMODEL / 4);
    transpose_bf16_kernel<<<dim3(NXZ / 32, DMODEL / 32), 256, 0, stream>>>(W_in, W_in_t, DMODEL, NXZ);
    transpose_bf16_kernel<<<dim3(DMODEL / 32, DINNER / 32), 256, 0, stream>>>(W_out, W_out_t, DINNER, DMODEL);

    // 1) xz = x @ W_in   (MFMA bf16, f32 out)
    gemm_bt_mfma<<<dim3(NXZ / 128, MROWS / 128), 256, 0, stream>>>(xb, W_in_t, xz, MROWS, NXZ, DMODEL);
    // 2) xs = silu(causal depthwise conv(xc) + conv_b)
    conv_silu_kernel<<<(MROWS * DINNER) / 256, 256, 0, stream>>>(xz, conv_w, conv_b, xs);
    // 3) dBC = xs @ W_x
    xproj_kernel<<<MROWS / 8, 256, 0, stream>>>(xs, W_x, dBC);
    // 4) chunked scan (delta fused on the fly); scanC writes bf16 ygb
    scanA_kernel<<<(BB * NC * DINNER) / 256, 256, 0, stream>>>(xs, dBC, A_log, W_dt, b_dt, aProd, hEnd);
    scanB_kernel<<<(BB * DSTATE * DINNER) / 256, 256, 0, stream>>>(aProd, hEnd);
    scanC_kernel<<<(BB * NC * DINNER) / 256, 256, 0, stream>>>(xz, xs, dBC, A_log, W_dt, b_dt, Dp, hEnd, ygb);
    // 5) out = yg @ W_out  (MFMA bf16, f32 out)
    gemm_bt_mfma<<<dim3(DMODEL / 128, MROWS / 128), 256, 0, stream>>>(ygb, W_out_t, out, MROWS, DMODEL, DINNER);
}